// Round 15
// baseline (215.219 us; speedup 1.0000x reference)
//
#include <hip/hip_runtime.h>
#include <hip/hip_bf16.h>
#include <stdint.h>

typedef unsigned short u16;
typedef __attribute__((ext_vector_type(4))) float f32x4;
typedef __attribute__((ext_vector_type(16))) float f32x16;
typedef __attribute__((ext_vector_type(8))) __bf16 bf16x8;
typedef __attribute__((ext_vector_type(2))) unsigned int u32x2;

__device__ __forceinline__ u16 f2bf(float f) {
  union { float f; uint32_t u; } x; x.f = f;
  const uint32_t u = x.u;
  return (u16)((u + 0x7fffu + ((u >> 16) & 1u)) >> 16);
}

// Q pre-scale: 1/sqrt(64) * log2(e), so softmax runs in exp2 domain.
#define QSCALE 0.1803368801111244f

// ------------------------------------------------------- fp32 -> bf16 cast
__global__ void cvt_f32_bf16(const float* __restrict__ in, u16* __restrict__ out,
                             int n) {
  const int i = (blockIdx.x * blockDim.x + threadIdx.x) * 4;
  if (i < n) {
    const float4 v = *(const float4*)(in + i);
    ushort4 o;
    o.x = f2bf(v.x); o.y = f2bf(v.y); o.z = f2bf(v.z); o.w = f2bf(v.w);
    *(ushort4*)(out + i) = o;
  }
}

// ------------------------- transpose + cast: f32 [R][Cc] -> bf16 [Cc][R]
__global__ void transpose_cvt(const float* __restrict__ in, u16* __restrict__ out,
                              int R, int Cc) {
  __shared__ u16 tile[64][66];
  const int tx = threadIdx.x, ty = threadIdx.y;
  const int c0 = blockIdx.x * 64, r0 = blockIdx.y * 64;
#pragma unroll
  for (int i = 0; i < 4; ++i)
    tile[ty + i * 16][tx] = f2bf(in[(size_t)(r0 + ty + i * 16) * Cc + c0 + tx]);
  __syncthreads();
#pragma unroll
  for (int i = 0; i < 4; ++i)
    out[(size_t)(c0 + ty + i * 16) * R + r0 + tx] = tile[tx][ty + i * 16];
}

// ---------------- per-head V transpose: [2048][64] -> [64][2048] (bf16)
__global__ void transpose_v(const u16* __restrict__ V, u16* __restrict__ VT) {
  __shared__ u16 tile[64][66];
  const int tx = threadIdx.x, ty = threadIdx.y;
  const int r0 = blockIdx.x * 64;                 // t-tile
  const size_t ho = (size_t)blockIdx.y * 2048 * 64;
  const u16* in = V + ho;
  u16* out = VT + ho;
#pragma unroll
  for (int i = 0; i < 4; ++i)
    tile[ty + i * 16][tx] = in[(size_t)(r0 + ty + i * 16) * 64 + tx];
  __syncthreads();
#pragma unroll
  for (int i = 0; i < 4; ++i)
    out[(size_t)(ty + i * 16) * 2048 + r0 + tx] = tile[tx][ty + i * 16];
}

// ------------------------------------------------ 8-phase 256x256 QKV GEMM
// A [M][K], BT [N][K] bf16. 512 thr = 8 waves (2M x 4N), wave tile 128x64.
// BK=64, double-buffered LDS halves, one half-tile staged per phase via
// global_load_lds(16B); raw s_barrier (never __syncthreads: it drains vmcnt);
// counted s_waitcnt vmcnt(4) ONLY at phases 4 and 8 (stage schedule below
// guarantees the latest-needed half always has exactly 2 stages after it).
// Stage slots (iter j): ph1 d1.Bh1[2j+1], ph2 d1.Ah1[2j+1], ph3 d0.Bh0[2j+2],
// ph4 d0.Ah0[2j+2], ph5 d0.Bh1[2j+2], ph6 d0.Ah1[2j+2], ph7 d1.Bh0[2j+3],
// ph8 d1.Ah0[2j+3]. Every overwrite lands >=1 phase after the half's last
// ds_read (reads: A-halves ph1/ph3(+ph5/ph7), B-halves ph1-2 (+ph5-6)).
// Epilogue: QKV scatter with Q pre-scaled by QSCALE.
__global__ __launch_bounds__(512, 2) void gemm8p_qkv(
    const u16* __restrict__ A, const u16* __restrict__ BT,
    u16* __restrict__ Qo, u16* __restrict__ Ko, u16* __restrict__ Vo,
    int K) {
  __shared__ u16 L[2][2][2][128 * 64];  // [dbuf][op:0=A,1=B][half][r*64+k]
  const int tid = threadIdx.x, wid = tid >> 6, lane = tid & 63;
  const int wm = wid >> 2, wn = wid & 3;
  const int l15 = lane & 15, l4 = lane >> 4;
  const int bn = blockIdx.x, bm = blockIdx.y;

  const u16* Atile = A + (size_t)bm * 256 * K;
  const u16* Btile = BT + (size_t)bn * 256 * K;

  f32x4 acc[8][4] = {};
  bf16x8 aF[4][2], bF[4][2];
  const int cb = wid * 64 + lane;

#define SB8() __builtin_amdgcn_sched_barrier(0)
#define BAR8() { SB8(); __builtin_amdgcn_s_barrier(); SB8(); }
#define VW4() { SB8(); asm volatile("s_waitcnt vmcnt(4)" ::: "memory"); SB8(); }
// stage one half-tile (128 rows x 64 cols) of op into L[d][op][h]
#define STG(d, op, h, kt) { \
    const u16* s0_ = ((op) ? Btile : Atile) + (size_t)(h) * 128 * K + (size_t)(kt) * 64; \
    _Pragma("unroll") for (int j_ = 0; j_ < 2; ++j_) { \
      const int c_ = j_ * 512 + cb; \
      __builtin_amdgcn_global_load_lds( \
          (const __attribute__((address_space(1))) uint32_t*)(s0_ + (size_t)(c_ >> 3) * K + (c_ & 7) * 8), \
          (__attribute__((address_space(3))) uint32_t*)(&L[d][op][h][(j_ * 512 + wid * 64) * 8]), 16, 0, 0); \
    } }
#define LD_A(d, mbase) { \
    _Pragma("unroll") for (int m_ = 0; m_ < 4; ++m_) \
    _Pragma("unroll") for (int k_ = 0; k_ < 2; ++k_) \
      aF[m_][k_] = *(const bf16x8*)&L[d][0][wm][(((mbase) + m_) * 16 + l15) * 64 + k_ * 32 + l4 * 8]; }
#define LD_B(d, nbase) { \
    _Pragma("unroll") for (int n_ = 0; n_ < 2; ++n_) \
    _Pragma("unroll") for (int k_ = 0; k_ < 2; ++k_) \
      bF[(nbase) + n_][k_] = *(const bf16x8*)&L[d][1][wn >> 1][((wn & 1) * 64 + ((nbase) + n_) * 16 + l15) * 64 + k_ * 32 + l4 * 8]; }
#define MQ(MS, NS) { __builtin_amdgcn_s_setprio(1); \
    _Pragma("unroll") for (int m_ = 0; m_ < 4; ++m_) \
    _Pragma("unroll") for (int n_ = 0; n_ < 2; ++n_) \
    _Pragma("unroll") for (int kk_ = 0; kk_ < 2; ++kk_) \
      acc[(MS) * 4 + m_][(NS) * 2 + n_] = __builtin_amdgcn_mfma_f32_16x16x32_bf16( \
          aF[m_][kk_], bF[(NS) * 2 + n_][kk_], acc[(MS) * 4 + m_][(NS) * 2 + n_], 0, 0, 0); \
    __builtin_amdgcn_s_setprio(0); }

  // prologue: slots "ph3..ph8 of iter -1" -> d0 full [tile0], d1 Bh0/Ah0 [tile1]
  STG(0, 1, 0, 0); STG(0, 0, 0, 0); STG(0, 1, 1, 0); STG(0, 0, 1, 0);
  STG(1, 1, 0, 1); STG(1, 0, 0, 1);
  VW4();   // <=4 outstanding -> d0[0] (8 oldest) landed
  BAR8();

  const int nkt = K >> 6;  // 16
  for (int it = 0; it < nkt / 2; ++it) {
    const int t1 = 2 * it + 1;
    const int t2 = (2 * it + 2 < nkt) ? 2 * it + 2 : nkt - 1;  // clamp: final
    const int t3 = (2 * it + 3 < nkt) ? 2 * it + 3 : nkt - 1;  // stages no-op
    // ph1: quadrant (m0-3, n0-1) of d0
    LD_A(0, 0); LD_B(0, 0);
    STG(1, 1, 1, t1);
    BAR8(); MQ(0, 0); BAR8();
    // ph2: (m0-3, n2-3)
    LD_B(0, 2);
    STG(1, 0, 1, t1);
    BAR8(); MQ(0, 1); BAR8();
    // ph3: (m4-7, n0-1)
    LD_A(0, 4);
    STG(0, 1, 0, t2);
    BAR8(); MQ(1, 0); BAR8();
    // ph4: (m4-7, n2-3); vmcnt(4) -> d1[t1] fully landed for ph5 reads
    STG(0, 0, 0, t2);
    VW4();
    BAR8(); MQ(1, 1); BAR8();
    // ph5: d1 (m0-3, n0-1)
    LD_A(1, 0); LD_B(1, 0);
    STG(0, 1, 1, t2);
    BAR8(); MQ(0, 0); BAR8();
    // ph6
    LD_B(1, 2);
    STG(0, 0, 1, t2);
    BAR8(); MQ(0, 1); BAR8();
    // ph7
    LD_A(1, 4);
    STG(1, 1, 0, t3);
    BAR8(); MQ(1, 0); BAR8();
    // ph8; vmcnt(4) -> d0[t2] fully landed for next ph1 reads
    STG(1, 0, 0, t3);
    VW4();
    BAR8(); MQ(1, 1); BAR8();
  }
  asm volatile("s_waitcnt vmcnt(0)" ::: "memory");  // drain trailing stages

  // epilogue: QKV scatter (row = M index, col = 3C index)
  const int row0 = bm * 256 + wm * 128;
  const int col0 = bn * 256 + wn * 64;
#pragma unroll
  for (int m = 0; m < 8; ++m) {
#pragma unroll
    for (int n = 0; n < 4; ++n) {
#pragma unroll
      for (int jj = 0; jj < 4; ++jj) {
        const int row = row0 + m * 16 + l4 * 4 + jj;
        const int col = col0 + n * 16 + l15;
        const int sec = col >> 10, c = col & 1023;
        const int h = c >> 6, d = c & 63;
        const int b = row >> 11, t = row & 2047;
        float av = acc[m][n][jj];
        if (sec == 0) av *= QSCALE;
        u16* dst = (sec == 0) ? Qo : (sec == 1) ? Ko : Vo;
        dst[(((size_t)(b * 16 + h)) * 2048 + t) * 64 + d] = f2bf(av);
      }
    }
  }
#undef SB8
#undef BAR8
#undef VW4
#undef STG
#undef LD_A
#undef LD_B
#undef MQ
}

// ---------------------------------------------------------------- GEMM (proj)
// A [M][K] bf16 row-major, BT [N][K] bf16 (B transposed). 128x128 tile, BK=32.
// Writes out[M][N] as FP32.
__global__ __launch_bounds__(256) void gemm_bt(
    const u16* __restrict__ A, const u16* __restrict__ BT,
    float* __restrict__ out, int M, int N, int K) {
  __shared__ u16 Asm_[128 * 32];
  __shared__ u16 Bsm_[128 * 32];
  const int tid = threadIdx.x;
  const int wid = tid >> 6, lane = tid & 63;
  const int wm = wid >> 1, wn = wid & 1;
  const int l15 = lane & 15, l4 = lane >> 4;
  const int bm = blockIdx.y, bn = blockIdx.x;

  const u16* Ag = A + (size_t)bm * 128 * K;
  const u16* Bg = BT + (size_t)bn * 128 * K;

  f32x4 acc[4][4] = {};

  const int srow = lane >> 2;        // 0..15
  const int scol = (lane & 3) * 8;   // 0,8,16,24

  for (int kt = 0; kt < K; kt += 32) {
    __syncthreads();  // previous tile's LDS reads done
#pragma unroll
    for (int it = 0; it < 2; ++it) {
      const int c = it * 4 + wid;  // 0..7, wave-uniform
      const int row = c * 16 + srow;
      __builtin_amdgcn_global_load_lds(
          (const __attribute__((address_space(1))) uint32_t*)(Ag + (size_t)row * K + kt + scol),
          (__attribute__((address_space(3))) uint32_t*)(&Asm_[c * 512]), 16, 0, 0);
      __builtin_amdgcn_global_load_lds(
          (const __attribute__((address_space(1))) uint32_t*)(Bg + (size_t)row * K + kt + scol),
          (__attribute__((address_space(3))) uint32_t*)(&Bsm_[c * 512]), 16, 0, 0);
    }
    __syncthreads();  // drains vmcnt(0) -> LDS ready

    bf16x8 af[4], bfr[4];
#pragma unroll
    for (int m = 0; m < 4; ++m)
      af[m] = *(const bf16x8*)&Asm_[(wm * 64 + m * 16 + l15) * 32 + l4 * 8];
#pragma unroll
    for (int n = 0; n < 4; ++n)
      bfr[n] = *(const bf16x8*)&Bsm_[(wn * 64 + n * 16 + l15) * 32 + l4 * 8];
#pragma unroll
    for (int m = 0; m < 4; ++m)
#pragma unroll
      for (int n = 0; n < 4; ++n)
        acc[m][n] = __builtin_amdgcn_mfma_f32_16x16x32_bf16(af[m], bfr[n], acc[m][n], 0, 0, 0);
  }

  const int row0 = bm * 128 + wm * 64;
  const int col0 = bn * 128 + wn * 64;
#pragma unroll
  for (int m = 0; m < 4; ++m)
#pragma unroll
    for (int n = 0; n < 4; ++n)
#pragma unroll
      for (int j = 0; j < 4; ++j) {
        const int row = row0 + m * 16 + l4 * 4 + j;
        const int col = col0 + n * 16 + l15;
        out[(size_t)row * N + col] = acc[m][n][j];
      }
}

// ---------------------------------------------------------------- attention
// Q,K [B,H,T,D] bf16 (Q pre-scaled by QSCALE); VT [B,H,D,T] bf16.
// Y [B*T][C] bf16 (c = h*64+d). grid (16,64), block 256 (4 waves x 32 q-rows).
// Swapped-MFMA + dbuf LDS + per-lane scalar softmax (see R11-R14 notes).
__global__ __launch_bounds__(256, 4) void attn_fwd(const u16* __restrict__ Qp,
                                                   const u16* __restrict__ Kp,
                                                   const u16* __restrict__ VTp,
                                                   u16* __restrict__ Y) {
  constexpr int DP = 72;       // padded row (16B-aligned)
  constexpr float THR = 11.0f; // defer-max threshold (log2-units; P <= 2^11)
  __shared__ u16 Ks[2][64 * DP];  // K[key][d], double-buffered
  __shared__ u16 Vt[2][64 * DP];  // V^T[d][key], double-buffered

  const int xorm = (int)((0x0A050F00u >> ((blockIdx.y >> 4) * 8)) & 15u);  // {0,15,5,10}
  const int qt = (int)blockIdx.x ^ xorm;  // 128-row q-tile (bijective remap)
  const int bh = blockIdx.y;
  const int b = bh >> 4, h = bh & 15;
  const int tid = threadIdx.x, lane = tid & 63;
  const int wid = tid >> 6;
  const int l31 = lane & 31, hb = lane >> 5;

  const size_t head_off = (size_t)bh * 2048 * 64;
  const u16* Kh = Kp + head_off;     // [2048][64]
  const u16* VTh = VTp + head_off;   // [64][2048]

  const int qg = qt * 128 + wid * 32 + l31;  // my q row within head
  const u16* Qrow = Qp + head_off + (size_t)qg * 64;

  bf16x8 qf[4];
#pragma unroll
  for (int d = 0; d < 4; ++d)
    qf[d] = *(const bf16x8*)(Qrow + d * 16 + hb * 8);

  float m_ = -1e30f, l_ = 0.f;
  f32x16 oacc[2] = {};  // O^T: col=q=l31; rows d = (r&3)+8*(r>>2)+4*hb +32*nb

  const int sr = tid >> 3;          // rows for it=0: 0..31; it=1: +32
  const int sc = (tid & 7) * 8;

  bf16x8 kreg[2], vreg[2];
  auto kvload = [&](int kt) {
#pragma unroll
    for (int it = 0; it < 2; ++it) {
      const int r = sr + it * 32;
      kreg[it] = *(const bf16x8*)(Kh + (size_t)(kt * 64 + r) * 64 + sc);
      vreg[it] = *(const bf16x8*)(VTh + (size_t)r * 2048 + kt * 64 + sc);
    }
  };
  auto kvwrite = [&](int buf) {
#pragma unroll
    for (int it = 0; it < 2; ++it) {
      const int r = sr + it * 32;
      *(bf16x8*)&Ks[buf][r * DP + sc] = kreg[it];
      *(bf16x8*)&Vt[buf][r * DP + sc] = vreg[it];
    }
  };

  kvload(0);
  kvwrite(0);
  __syncthreads();

  const int nt = 2 * qt + 2;
  for (int kt = 0; kt < nt; ++kt) {
    const int cur = kt & 1;
    const bool havenext = (kt + 1 < nt);
    if (havenext) kvload(kt + 1);  // issue early; lands after compute

    const bool diag = (kt >= 2 * qt);

#pragma unroll
    for (int kb2 = 0; kb2 < 2; ++kb2) {  // 32-key subtile
      f32x16 s = {};
      __builtin_amdgcn_s_setprio(1);
#pragma unroll
      for (int d = 0; d < 4; ++d) {
        const bf16x8 kf = *(const bf16x8*)&Ks[cur][(kb2 * 32 + l31) * DP + d * 16 + hb * 8];
        s = __builtin_amdgcn_mfma_f32_32x32x16_bf16(kf, qf[d], s, 0, 0, 0);
      }
      __builtin_amdgcn_s_setprio(0);

      if (diag) {
        const int kbase = kt * 64 + kb2 * 32 + hb * 4;
#pragma unroll
        for (int r = 0; r < 16; ++r) {
          const int koff = (r & 3) + 8 * (r >> 2);
          if (kbase + koff > qg) s[r] = -1e30f;
        }
      }

      float pmax = s[0];
#pragma unroll
      for (int r = 1; r < 16; ++r) pmax = fmaxf(pmax, s[r]);
      if (!__all(pmax - m_ <= THR)) {
        const float fm = fmaxf(pmax, __shfl_xor(pmax, 32));
        const float mnew = fmaxf(m_, fm);
        const float alpha = __builtin_exp2f(m_ - mnew);
        m_ = mnew;
        l_ *= alpha;
#pragma unroll
        for (int nb = 0; nb < 2; ++nb)
#pragma unroll
          for (int r = 0; r < 16; ++r) oacc[nb][r] *= alpha;
      }
#pragma unroll
      for (int r = 0; r < 16; ++r) {
        s[r] = __builtin_exp2f(s[r] - m_);
        l_ += s[r];
      }

      bf16x8 pb[2];
#pragma unroll
      for (int st = 0; st < 2; ++st) {
        uint32_t x0, x1, y0, y1;
        asm("v_cvt_pk_bf16_f32 %0, %1, %2" : "=v"(x0) : "v"(s[8 * st + 0]), "v"(s[8 * st + 1]));
        asm("v_cvt_pk_bf16_f32 %0, %1, %2" : "=v"(x1) : "v"(s[8 * st + 2]), "v"(s[8 * st + 3]));
        asm("v_cvt_pk_bf16_f32 %0, %1, %2" : "=v"(y0) : "v"(s[8 * st + 4]), "v"(s[8 * st + 5]));
        asm("v_cvt_pk_bf16_f32 %0, %1, %2" : "=v"(y1) : "v"(s[8 * st + 6]), "v"(s[8 * st + 7]));
        const u32x2 r0 = __builtin_amdgcn_permlane32_swap(x0, y0, false, false);
        const u32x2 r1 = __builtin_amdgcn_permlane32_swap(x1, y1, false, false);
        union { uint32_t w[4]; bf16x8 v; } u;
        u.w[0] = r0[0]; u.w[1] = r1[0]; u.w[2] = r0[1]; u.w[3] = r1[1];
        pb[st] = u.v;
      }

      __builtin_amdgcn_s_setprio(1);
#pragma unroll
      for (int nb = 0; nb < 2; ++nb)
#pragma unroll
        for (int st = 0; st < 2; ++st) {
          const bf16x8 vf = *(const bf16x8*)&Vt[cur][(nb * 32 + l31) * DP + kb2 * 32 + st * 16 + hb * 8];
          oacc[nb] = __builtin_amdgcn_mfma_f32_32x32x16_bf16(vf, pb[st], oacc[nb], 0, 0, 0);
        }
      __builtin_amdgcn_s_setprio(0);
    }

    if (havenext) kvwrite(cur ^ 1);
    __syncthreads();
  }

  const float lf = l_ + __shfl_xor(l_, 32);
  const float inv = 1.0f / lf;
  u16* Yrow = Y + ((size_t)b * 2048 + qg) * 1024 + h * 64;
#pragma unroll
  for (int nb = 0; nb < 2; ++nb) {
#pragma unroll
    for (int g = 0; g < 4; ++g) {  // d = 8g + 4hb + 32nb + (0..3)
      ushort4 o;
      o.x = f2bf(oacc[nb][4 * g + 0] * inv);
      o.y = f2bf(oacc[nb][4 * g + 1] * inv);
      o.z = f2bf(oacc[nb][4 * g + 2] * inv);
      o.w = f2bf(oacc[nb][4 * g + 3] * inv);
      *(ushort4*)(Yrow + nb * 32 + g * 8 + hb * 4) = o;
    }
  }
}

// ---------------------------------------------------------------- launch
extern "C" void kernel_launch(void* const* d_in, const int* in_sizes, int n_in,
                              void* d_out, int out_size, void* d_ws,
                              size_t ws_size, hipStream_t stream) {
  const float* x = (const float*)d_in[0];       // [4,2048,1024] fp32
  const float* w_qkv = (const float*)d_in[1];   // [1024,3072] fp32
  const float* w_proj = (const float*)d_in[2];  // [1024,1024] fp32
  float* out = (float*)d_out;                   // [4,2048,1024] fp32

  char* ws = (char*)d_ws;
  u16* xb = (u16*)ws;                          // [8192][1024]  16 MB (dead after QKV GEMM)
  u16* VTw = (u16*)ws;                         // [B,H,D,T]     16 MB (aliases xb)
  u16* wqkvT = (u16*)(ws + 16777216);          // [3072][1024]   6 MB
  u16* wprojT = (u16*)(ws + 23068672);         // [1024][1024]   2 MB
  u16* Qw = (u16*)(ws + 25165824);             // [B,H,T,D]     16 MB
  u16* Kw = (u16*)(ws + 41943040);             // 16 MB
  u16* Vw = (u16*)(ws + 58720256);             // 16 MB
  u16* Yw = (u16*)(ws + 75497472);             // [B*T][C]      16 MB
  if (ws_size < 92274688) return;  // distinguishable failure (abs=ref max)

  cvt_f32_bf16<<<dim3(8192), dim3(256), 0, stream>>>(x, xb, 8388608);

  dim3 tb(64, 16);
  transpose_cvt<<<dim3(48, 16), tb, 0, stream>>>(w_qkv, wqkvT, 1024, 3072);
  transpose_cvt<<<dim3(16, 16), tb, 0, stream>>>(w_proj, wprojT, 1024, 1024);

  gemm8p_qkv<<<dim3(12, 32), dim3(512), 0, stream>>>(
      xb, wqkvT, Qw, Kw, Vw, 1024);

  // xb is dead now; build VT in its place.
  transpose_v<<<dim3(32, 64), tb, 0, stream>>>(Vw, VTw);

  attn_fwd<<<dim3(16, 64), dim3(256), 0, stream>>>(Qw, Kw, VTw, Yw);

  gemm_bt<<<dim3(8, 64), dim3(256), 0, stream>>>(
      Yw, wprojT, out, 8192, 1024, 1024);
}

// Round 16
// 193.777 us; speedup vs baseline: 1.1107x; 1.1107x over previous
//
#include <hip/hip_runtime.h>
#include <hip/hip_bf16.h>
#include <stdint.h>

typedef unsigned short u16;
typedef __attribute__((ext_vector_type(4))) float f32x4;
typedef __attribute__((ext_vector_type(16))) float f32x16;
typedef __attribute__((ext_vector_type(8))) __bf16 bf16x8;
typedef __attribute__((ext_vector_type(2))) unsigned int u32x2;

__device__ __forceinline__ u16 f2bf(float f) {
  union { float f; uint32_t u; } x; x.f = f;
  const uint32_t u = x.u;
  return (u16)((u + 0x7fffu + ((u >> 16) & 1u)) >> 16);
}

// Q pre-scale: 1/sqrt(64) * log2(e), so softmax runs in exp2 domain.
#define QSCALE 0.1803368801111244f

// ------------------------------------------------------- fp32 -> bf16 cast
__global__ void cvt_f32_bf16(const float* __restrict__ in, u16* __restrict__ out,
                             int n) {
  const int i = (blockIdx.x * blockDim.x + threadIdx.x) * 4;
  if (i < n) {
    const float4 v = *(const float4*)(in + i);
    ushort4 o;
    o.x = f2bf(v.x); o.y = f2bf(v.y); o.z = f2bf(v.z); o.w = f2bf(v.w);
    *(ushort4*)(out + i) = o;
  }
}

// ------------------------- transpose + cast: f32 [R][Cc] -> bf16 [Cc][R]
__global__ void transpose_cvt(const float* __restrict__ in, u16* __restrict__ out,
                              int R, int Cc) {
  __shared__ u16 tile[64][66];
  const int tx = threadIdx.x, ty = threadIdx.y;
  const int c0 = blockIdx.x * 64, r0 = blockIdx.y * 64;
#pragma unroll
  for (int i = 0; i < 4; ++i)
    tile[ty + i * 16][tx] = f2bf(in[(size_t)(r0 + ty + i * 16) * Cc + c0 + tx]);
  __syncthreads();
#pragma unroll
  for (int i = 0; i < 4; ++i)
    out[(size_t)(c0 + ty + i * 16) * R + r0 + tx] = tile[tx][ty + i * 16];
}

// ---------------- per-head V transpose: [2048][64] -> [64][2048] (bf16)
__global__ void transpose_v(const u16* __restrict__ V, u16* __restrict__ VT) {
  __shared__ u16 tile[64][66];
  const int tx = threadIdx.x, ty = threadIdx.y;
  const int r0 = blockIdx.x * 64;                 // t-tile
  const size_t ho = (size_t)blockIdx.y * 2048 * 64;
  const u16* in = V + ho;
  u16* out = VT + ho;
#pragma unroll
  for (int i = 0; i < 4; ++i)
    tile[ty + i * 16][tx] = in[(size_t)(r0 + ty + i * 16) * 64 + tx];
  __syncthreads();
#pragma unroll
  for (int i = 0; i < 4; ++i)
    out[(size_t)(ty + i * 16) * 2048 + r0 + tx] = tile[tx][ty + i * 16];
}

// ------------------------------------------------ 8-phase 256x256 QKV GEMM
// As R15, + T2 swizzle (rule #21: LDS linear for global_load_lds; global
// SOURCE pre-permuted with g=(c&7)^(r&7); ds_read applies the same
// involution granule=(k*4+l4)^(l15&7)). Kills the 16-way conflict of
// 128B-row linear LDS (all l15 lanes same bank column).
__global__ __launch_bounds__(512, 2) void gemm8p_qkv(
    const u16* __restrict__ A, const u16* __restrict__ BT,
    u16* __restrict__ Qo, u16* __restrict__ Ko, u16* __restrict__ Vo,
    int K) {
  __shared__ u16 L[2][2][2][128 * 64];  // [dbuf][op:0=A,1=B][half][r*64+k]
  const int tid = threadIdx.x, wid = tid >> 6, lane = tid & 63;
  const int wm = wid >> 2, wn = wid & 3;
  const int l15 = lane & 15, l4 = lane >> 4;
  const int bn = blockIdx.x, bm = blockIdx.y;

  const u16* Atile = A + (size_t)bm * 256 * K;
  const u16* Btile = BT + (size_t)bn * 256 * K;

  f32x4 acc[8][4] = {};
  bf16x8 aF[4][2], bF[4][2];
  const int cb = wid * 64 + lane;

#define SB8() __builtin_amdgcn_sched_barrier(0)
#define BAR8() { SB8(); __builtin_amdgcn_s_barrier(); SB8(); }
#define VW4() { SB8(); asm volatile("s_waitcnt vmcnt(4)" ::: "memory"); SB8(); }
// stage one half-tile (128 rows x 64 cols) of op into L[d][op][h].
// LDS dest linear; global source granule-swizzled: g = (c&7) ^ (r&7).
#define STG(d, op, h, kt) { \
    const u16* s0_ = ((op) ? Btile : Atile) + (size_t)(h) * 128 * K + (size_t)(kt) * 64; \
    _Pragma("unroll") for (int j_ = 0; j_ < 2; ++j_) { \
      const int c_ = j_ * 512 + cb; \
      const int r_ = c_ >> 3; \
      const int g_ = (c_ & 7) ^ (r_ & 7); \
      __builtin_amdgcn_global_load_lds( \
          (const __attribute__((address_space(1))) uint32_t*)(s0_ + (size_t)r_ * K + g_ * 8), \
          (__attribute__((address_space(3))) uint32_t*)(&L[d][op][h][(j_ * 512 + wid * 64) * 8]), 16, 0, 0); \
    } }
#define LD_A(d, mbase) { \
    _Pragma("unroll") for (int m_ = 0; m_ < 4; ++m_) \
    _Pragma("unroll") for (int k_ = 0; k_ < 2; ++k_) \
      aF[m_][k_] = *(const bf16x8*)&L[d][0][wm][(((mbase) + m_) * 16 + l15) * 64 + (((k_ * 4 + l4) ^ (l15 & 7)) * 8)]; }
#define LD_B(d, nbase) { \
    _Pragma("unroll") for (int n_ = 0; n_ < 2; ++n_) \
    _Pragma("unroll") for (int k_ = 0; k_ < 2; ++k_) \
      bF[(nbase) + n_][k_] = *(const bf16x8*)&L[d][1][wn >> 1][((wn & 1) * 64 + ((nbase) + n_) * 16 + l15) * 64 + (((k_ * 4 + l4) ^ (l15 & 7)) * 8)]; }
#define MQ(MS, NS) { __builtin_amdgcn_s_setprio(1); \
    _Pragma("unroll") for (int m_ = 0; m_ < 4; ++m_) \
    _Pragma("unroll") for (int n_ = 0; n_ < 2; ++n_) \
    _Pragma("unroll") for (int kk_ = 0; kk_ < 2; ++kk_) \
      acc[(MS) * 4 + m_][(NS) * 2 + n_] = __builtin_amdgcn_mfma_f32_16x16x32_bf16( \
          aF[m_][kk_], bF[(NS) * 2 + n_][kk_], acc[(MS) * 4 + m_][(NS) * 2 + n_], 0, 0, 0); \
    __builtin_amdgcn_s_setprio(0); }

  // prologue: slots "ph3..ph8 of iter -1" -> d0 full [tile0], d1 Bh0/Ah0 [tile1]
  STG(0, 1, 0, 0); STG(0, 0, 0, 0); STG(0, 1, 1, 0); STG(0, 0, 1, 0);
  STG(1, 1, 0, 1); STG(1, 0, 0, 1);
  VW4();   // <=4 outstanding -> d0[0] (8 oldest) landed
  BAR8();

  const int nkt = K >> 6;  // 16
  for (int it = 0; it < nkt / 2; ++it) {
    const int t1 = 2 * it + 1;
    const int t2 = (2 * it + 2 < nkt) ? 2 * it + 2 : nkt - 1;  // clamp: final
    const int t3 = (2 * it + 3 < nkt) ? 2 * it + 3 : nkt - 1;  // stages no-op
    // ph1: quadrant (m0-3, n0-1) of d0
    LD_A(0, 0); LD_B(0, 0);
    STG(1, 1, 1, t1);
    BAR8(); MQ(0, 0); BAR8();
    // ph2: (m0-3, n2-3)
    LD_B(0, 2);
    STG(1, 0, 1, t1);
    BAR8(); MQ(0, 1); BAR8();
    // ph3: (m4-7, n0-1)
    LD_A(0, 4);
    STG(0, 1, 0, t2);
    BAR8(); MQ(1, 0); BAR8();
    // ph4: (m4-7, n2-3); vmcnt(4) -> d1[t1] fully landed for ph5 reads
    STG(0, 0, 0, t2);
    VW4();
    BAR8(); MQ(1, 1); BAR8();
    // ph5: d1 (m0-3, n0-1)
    LD_A(1, 0); LD_B(1, 0);
    STG(0, 1, 1, t2);
    BAR8(); MQ(0, 0); BAR8();
    // ph6
    LD_B(1, 2);
    STG(0, 0, 1, t2);
    BAR8(); MQ(0, 1); BAR8();
    // ph7
    LD_A(1, 4);
    STG(1, 1, 0, t3);
    BAR8(); MQ(1, 0); BAR8();
    // ph8; vmcnt(4) -> d0[t2] fully landed for next ph1 reads
    STG(1, 0, 0, t3);
    VW4();
    BAR8(); MQ(1, 1); BAR8();
  }
  asm volatile("s_waitcnt vmcnt(0)" ::: "memory");  // drain trailing stages

  // epilogue: QKV scatter (row = M index, col = 3C index)
  const int row0 = bm * 256 + wm * 128;
  const int col0 = bn * 256 + wn * 64;
#pragma unroll
  for (int m = 0; m < 8; ++m) {
#pragma unroll
    for (int n = 0; n < 4; ++n) {
#pragma unroll
      for (int jj = 0; jj < 4; ++jj) {
        const int row = row0 + m * 16 + l4 * 4 + jj;
        const int col = col0 + n * 16 + l15;
        const int sec = col >> 10, c = col & 1023;
        const int h = c >> 6, d = c & 63;
        const int b = row >> 11, t = row & 2047;
        float av = acc[m][n][jj];
        if (sec == 0) av *= QSCALE;
        u16* dst = (sec == 0) ? Qo : (sec == 1) ? Ko : Vo;
        dst[(((size_t)(b * 16 + h)) * 2048 + t) * 64 + d] = f2bf(av);
      }
    }
  }
#undef SB8
#undef BAR8
#undef VW4
#undef STG
#undef LD_A
#undef LD_B
#undef MQ
}

// ---------------------------------------------------------------- GEMM (proj)
// A [M][K] bf16 row-major, BT [N][K] bf16 (B transposed). 128x128 tile, BK=32.
// Writes out[M][N] as FP32.
__global__ __launch_bounds__(256) void gemm_bt(
    const u16* __restrict__ A, const u16* __restrict__ BT,
    float* __restrict__ out, int M, int N, int K) {
  __shared__ u16 Asm_[128 * 32];
  __shared__ u16 Bsm_[128 * 32];
  const int tid = threadIdx.x;
  const int wid = tid >> 6, lane = tid & 63;
  const int wm = wid >> 1, wn = wid & 1;
  const int l15 = lane & 15, l4 = lane >> 4;
  const int bm = blockIdx.y, bn = blockIdx.x;

  const u16* Ag = A + (size_t)bm * 128 * K;
  const u16* Bg = BT + (size_t)bn * 128 * K;

  f32x4 acc[4][4] = {};

  const int srow = lane >> 2;        // 0..15
  const int scol = (lane & 3) * 8;   // 0,8,16,24

  for (int kt = 0; kt < K; kt += 32) {
    __syncthreads();  // previous tile's LDS reads done
#pragma unroll
    for (int it = 0; it < 2; ++it) {
      const int c = it * 4 + wid;  // 0..7, wave-uniform
      const int row = c * 16 + srow;
      __builtin_amdgcn_global_load_lds(
          (const __attribute__((address_space(1))) uint32_t*)(Ag + (size_t)row * K + kt + scol),
          (__attribute__((address_space(3))) uint32_t*)(&Asm_[c * 512]), 16, 0, 0);
      __builtin_amdgcn_global_load_lds(
          (const __attribute__((address_space(1))) uint32_t*)(Bg + (size_t)row * K + kt + scol),
          (__attribute__((address_space(3))) uint32_t*)(&Bsm_[c * 512]), 16, 0, 0);
    }
    __syncthreads();  // drains vmcnt(0) -> LDS ready

    bf16x8 af[4], bfr[4];
#pragma unroll
    for (int m = 0; m < 4; ++m)
      af[m] = *(const bf16x8*)&Asm_[(wm * 64 + m * 16 + l15) * 32 + l4 * 8];
#pragma unroll
    for (int n = 0; n < 4; ++n)
      bfr[n] = *(const bf16x8*)&Bsm_[(wn * 64 + n * 16 + l15) * 32 + l4 * 8];
#pragma unroll
    for (int m = 0; m < 4; ++m)
#pragma unroll
      for (int n = 0; n < 4; ++n)
        acc[m][n] = __builtin_amdgcn_mfma_f32_16x16x32_bf16(af[m], bfr[n], acc[m][n], 0, 0, 0);
  }

  const int row0 = bm * 128 + wm * 64;
  const int col0 = bn * 128 + wn * 64;
#pragma unroll
  for (int m = 0; m < 4; ++m)
#pragma unroll
    for (int n = 0; n < 4; ++n)
#pragma unroll
      for (int j = 0; j < 4; ++j) {
        const int row = row0 + m * 16 + l4 * 4 + j;
        const int col = col0 + n * 16 + l15;
        out[(size_t)row * N + col] = acc[m][n][j];
      }
}

// ---------------------------------------------------------------- attention
// Q,K [B,H,T,D] bf16 (Q pre-scaled by QSCALE); VT [B,H,D,T] bf16.
// Y [B*T][C] bf16 (c = h*64+d). grid (16,64), block 256 (4 waves x 32 q-rows).
// Swapped-MFMA + dbuf LDS + per-lane scalar softmax (see R11-R14 notes).
__global__ __launch_bounds__(256, 4) void attn_fwd(const u16* __restrict__ Qp,
                                                   const u16* __restrict__ Kp,
                                                   const u16* __restrict__ VTp,
                                                   u16* __restrict__ Y) {
  constexpr int DP = 72;       // padded row (16B-aligned)
  constexpr float THR = 11.0f; // defer-max threshold (log2-units; P <= 2^11)
  __shared__ u16 Ks[2][64 * DP];  // K[key][d], double-buffered
  __shared__ u16 Vt[2][64 * DP];  // V^T[d][key], double-buffered

  const int xorm = (int)((0x0A050F00u >> ((blockIdx.y >> 4) * 8)) & 15u);  // {0,15,5,10}
  const int qt = (int)blockIdx.x ^ xorm;  // 128-row q-tile (bijective remap)
  const int bh = blockIdx.y;
  const int b = bh >> 4, h = bh & 15;
  const int tid = threadIdx.x, lane = tid & 63;
  const int wid = tid >> 6;
  const int l31 = lane & 31, hb = lane >> 5;

  const size_t head_off = (size_t)bh * 2048 * 64;
  const u16* Kh = Kp + head_off;     // [2048][64]
  const u16* VTh = VTp + head_off;   // [64][2048]

  const int qg = qt * 128 + wid * 32 + l31;  // my q row within head
  const u16* Qrow = Qp + head_off + (size_t)qg * 64;

  bf16x8 qf[4];
#pragma unroll
  for (int d = 0; d < 4; ++d)
    qf[d] = *(const bf16x8*)(Qrow + d * 16 + hb * 8);

  float m_ = -1e30f, l_ = 0.f;
  f32x16 oacc[2] = {};  // O^T: col=q=l31; rows d = (r&3)+8*(r>>2)+4*hb +32*nb

  const int sr = tid >> 3;          // rows for it=0: 0..31; it=1: +32
  const int sc = (tid & 7) * 8;

  bf16x8 kreg[2], vreg[2];
  auto kvload = [&](int kt) {
#pragma unroll
    for (int it = 0; it < 2; ++it) {
      const int r = sr + it * 32;
      kreg[it] = *(const bf16x8*)(Kh + (size_t)(kt * 64 + r) * 64 + sc);
      vreg[it] = *(const bf16x8*)(VTh + (size_t)r * 2048 + kt * 64 + sc);
    }
  };
  auto kvwrite = [&](int buf) {
#pragma unroll
    for (int it = 0; it < 2; ++it) {
      const int r = sr + it * 32;
      *(bf16x8*)&Ks[buf][r * DP + sc] = kreg[it];
      *(bf16x8*)&Vt[buf][r * DP + sc] = vreg[it];
    }
  };

  kvload(0);
  kvwrite(0);
  __syncthreads();

  const int nt = 2 * qt + 2;
  for (int kt = 0; kt < nt; ++kt) {
    const int cur = kt & 1;
    const bool havenext = (kt + 1 < nt);
    if (havenext) kvload(kt + 1);  // issue early; lands after compute

    const bool diag = (kt >= 2 * qt);

#pragma unroll
    for (int kb2 = 0; kb2 < 2; ++kb2) {  // 32-key subtile
      f32x16 s = {};
      __builtin_amdgcn_s_setprio(1);
#pragma unroll
      for (int d = 0; d < 4; ++d) {
        const bf16x8 kf = *(const bf16x8*)&Ks[cur][(kb2 * 32 + l31) * DP + d * 16 + hb * 8];
        s = __builtin_amdgcn_mfma_f32_32x32x16_bf16(kf, qf[d], s, 0, 0, 0);
      }
      __builtin_amdgcn_s_setprio(0);

      if (diag) {
        const int kbase = kt * 64 + kb2 * 32 + hb * 4;
#pragma unroll
        for (int r = 0; r < 16; ++r) {
          const int koff = (r & 3) + 8 * (r >> 2);
          if (kbase + koff > qg) s[r] = -1e30f;
        }
      }

      float pmax = s[0];
#pragma unroll
      for (int r = 1; r < 16; ++r) pmax = fmaxf(pmax, s[r]);
      if (!__all(pmax - m_ <= THR)) {
        const float fm = fmaxf(pmax, __shfl_xor(pmax, 32));
        const float mnew = fmaxf(m_, fm);
        const float alpha = __builtin_exp2f(m_ - mnew);
        m_ = mnew;
        l_ *= alpha;
#pragma unroll
        for (int nb = 0; nb < 2; ++nb)
#pragma unroll
          for (int r = 0; r < 16; ++r) oacc[nb][r] *= alpha;
      }
#pragma unroll
      for (int r = 0; r < 16; ++r) {
        s[r] = __builtin_exp2f(s[r] - m_);
        l_ += s[r];
      }

      bf16x8 pb[2];
#pragma unroll
      for (int st = 0; st < 2; ++st) {
        uint32_t x0, x1, y0, y1;
        asm("v_cvt_pk_bf16_f32 %0, %1, %2" : "=v"(x0) : "v"(s[8 * st + 0]), "v"(s[8 * st + 1]));
        asm("v_cvt_pk_bf16_f32 %0, %1, %2" : "=v"(x1) : "v"(s[8 * st + 2]), "v"(s[8 * st + 3]));
        asm("v_cvt_pk_bf16_f32 %0, %1, %2" : "=v"(y0) : "v"(s[8 * st + 4]), "v"(s[8 * st + 5]));
        asm("v_cvt_pk_bf16_f32 %0, %1, %2" : "=v"(y1) : "v"(s[8 * st + 6]), "v"(s[8 * st + 7]));
        const u32x2 r0 = __builtin_amdgcn_permlane32_swap(x0, y0, false, false);
        const u32x2 r1 = __builtin_amdgcn_permlane32_swap(x1, y1, false, false);
        union { uint32_t w[4]; bf16x8 v; } u;
        u.w[0] = r0[0]; u.w[1] = r1[0]; u.w[2] = r0[1]; u.w[3] = r1[1];
        pb[st] = u.v;
      }

      __builtin_amdgcn_s_setprio(1);
#pragma unroll
      for (int nb = 0; nb < 2; ++nb)
#pragma unroll
        for (int st = 0; st < 2; ++st) {
          const bf16x8 vf = *(const bf16x8*)&Vt[cur][(nb * 32 + l31) * DP + kb2 * 32 + st * 16 + hb * 8];
          oacc[nb] = __builtin_amdgcn_mfma_f32_32x32x16_bf16(vf, pb[st], oacc[nb], 0, 0, 0);
        }
      __builtin_amdgcn_s_setprio(0);
    }

    if (havenext) kvwrite(cur ^ 1);
    __syncthreads();
  }

  const float lf = l_ + __shfl_xor(l_, 32);
  const float inv = 1.0f / lf;
  u16* Yrow = Y + ((size_t)b * 2048 + qg) * 1024 + h * 64;
#pragma unroll
  for (int nb = 0; nb < 2; ++nb) {
#pragma unroll
    for (int g = 0; g < 4; ++g) {  // d = 8g + 4hb + 32nb + (0..3)
      ushort4 o;
      o.x = f2bf(oacc[nb][4 * g + 0] * inv);
      o.y = f2bf(oacc[nb][4 * g + 1] * inv);
      o.z = f2bf(oacc[nb][4 * g + 2] * inv);
      o.w = f2bf(oacc[nb][4 * g + 3] * inv);
      *(ushort4*)(Yrow + nb * 32 + g * 8 + hb * 4) = o;
    }
  }
}

// ---------------------------------------------------------------- launch
extern "C" void kernel_launch(void* const* d_in, const int* in_sizes, int n_in,
                              void* d_out, int out_size, void* d_ws,
                              size_t ws_size, hipStream_t stream) {
  const float* x = (const float*)d_in[0];       // [4,2048,1024] fp32
  const float* w_qkv = (const float*)d_in[1];   // [1024,3072] fp32
  const float* w_proj = (const float*)d_in[2];  // [1024,1024] fp32
  float* out = (float*)d_out;                   // [4,2048,1024] fp32

  char* ws = (char*)d_ws;
  u16* xb = (u16*)ws;                          // [8192][1024]  16 MB (dead after QKV GEMM)
  u16* VTw = (u16*)ws;                         // [B,H,D,T]     16 MB (aliases xb)
  u16* wqkvT = (u16*)(ws + 16777216);          // [3072][1024]   6 MB
  u16* wprojT = (u16*)(ws + 23068672);         // [1024][1024]   2 MB
  u16* Qw = (u16*)(ws + 25165824);             // [B,H,T,D]     16 MB
  u16* Kw = (u16*)(ws + 41943040);             // 16 MB
  u16* Vw = (u16*)(ws + 58720256);             // 16 MB
  u16* Yw = (u16*)(ws + 75497472);             // [B*T][C]      16 MB
  if (ws_size < 92274688) return;  // distinguishable failure (abs=ref max)

  cvt_f32_bf16<<<dim3(8192), dim3(256), 0, stream>>>(x, xb, 8388608);

  dim3 tb(64, 16);
  transpose_cvt<<<dim3(48, 16), tb, 0, stream>>>(w_qkv, wqkvT, 1024, 3072);
  transpose_cvt<<<dim3(16, 16), tb, 0, stream>>>(w_proj, wprojT, 1024, 1024);

  gemm8p_qkv<<<dim3(12, 32), dim3(512), 0, stream>>>(
      xb, wqkvT, Qw, Kw, Vw, 1024);

  // xb is dead now; build VT in its place.
  transpose_v<<<dim3(32, 64), tb, 0, stream>>>(Vw, VTw);

  attn_fwd<<<dim3(16, 64), dim3(256), 0, stream>>>(Qw, Kw, VTw, Yw);

  gemm_bt<<<dim3(8, 64), dim3(256), 0, stream>>>(
      Yw, wprojT, out, 8192, 1024, 1024);
}